// Round 8
// baseline (614.618 us; speedup 1.0000x reference)
//
#include <hip/hip_runtime.h>
#include <hip/hip_bf16.h>
#include <stdint.h>

#define TOKENS 8192
#define DDIM 1024
#define HDIM 4096
#define NEXP 8
#define MAXENT 16384
#define MAXTILES 136

typedef __attribute__((ext_vector_type(4))) float f32x4;
typedef __attribute__((ext_vector_type(8))) short bf16x8;
typedef __attribute__((ext_vector_type(4))) int i32x4;

__device__ __forceinline__ unsigned short f2bf(float f) {
  __hip_bfloat16 h = __float2bfloat16(f);
  return __builtin_bit_cast(unsigned short, h);
}

__device__ __forceinline__ void gload16(const void* g, void* l) {
  __builtin_amdgcn_global_load_lds(
      (const __attribute__((address_space(1))) unsigned int*)g,
      (__attribute__((address_space(3))) unsigned int*)l, 16, 0, 0);
}

__device__ __forceinline__ void bar() {
  asm volatile("" ::: "memory");
  __builtin_amdgcn_sched_barrier(0);
  __builtin_amdgcn_s_barrier();
  __builtin_amdgcn_sched_barrier(0);
  asm volatile("" ::: "memory");
}

#define VMWAIT(N) asm volatile("s_waitcnt vmcnt(" #N ")" ::: "memory")

// ---------------- prep ----------------

__global__ void moe_count(const int* __restrict__ idx, int* __restrict__ meta) {
  int t = blockIdx.x * 256 + threadIdx.x;
  if (t >= TOKENS) return;
  int e0 = idx[2 * t], e1 = idx[2 * t + 1];
  atomicAdd(&meta[e0], 1);
  if (e1 != e0) atomicAdd(&meta[e1], 1);
}

__global__ void moe_scan(int* __restrict__ meta) {
  if (threadIdx.x != 0 || blockIdx.x != 0) return;
  int s = 0;
  for (int e = 0; e < NEXP; ++e) { meta[16 + e] = s; meta[32 + e] = s; s += meta[e]; }
  meta[16 + NEXP] = s;
  int nt = 0;
  for (int e = 0; e < NEXP; ++e) {
    int m = (meta[e] + 127) >> 7;  // 128-entry tiles
    for (int t = 0; t < m; ++t) meta[64 + nt++] = e | (t << 8);
  }
  meta[48] = nt;
}

__global__ void moe_scatter(const int* __restrict__ idx, const float* __restrict__ ew,
                            int* __restrict__ meta, int* __restrict__ etok,
                            float* __restrict__ ewgt, int* __restrict__ inv) {
  int t = blockIdx.x * 256 + threadIdx.x;
  if (t >= TOKENS) return;
  int e0 = idx[2 * t], e1 = idx[2 * t + 1];
  float a = ew[2 * t], b = ew[2 * t + 1];
  if (e0 == e1) {
    int p = atomicAdd(&meta[32 + e0], 1);
    etok[p] = t; ewgt[p] = a + b;
    inv[2 * t] = p; inv[2 * t + 1] = -1;
  } else {
    int p = atomicAdd(&meta[32 + e0], 1);
    etok[p] = t; ewgt[p] = a;
    int q = atomicAdd(&meta[32 + e1], 1);
    etok[q] = t; ewgt[q] = b;
    inv[2 * t] = p; inv[2 * t + 1] = q;
  }
}

// ------- gather x into A-pretile pages: [page=mti][ktile(32)][chunk 8][lane 64][8] bf16 -------
// element: ent_local = chunk*16 + (lane&15); k = ktile*32 + (lane>>4)*8 + i

__global__ __launch_bounds__(256) void gather_pre(const float* __restrict__ x,
                                                  const int* __restrict__ etok,
                                                  const int* __restrict__ meta,
                                                  unsigned short* __restrict__ xgp) {
  int ntiles = meta[48];
  int page = blockIdx.x, kt = blockIdx.y;
  if (page >= ntiles) return;
  int te = meta[64 + page];
  int e = te & 255, mt = te >> 8;
  int ent0 = meta[16 + e] + mt * 128, lim = meta[16 + e + 1];
  int tid = threadIdx.x;
#pragma unroll
  for (int u2 = 0; u2 < 2; ++u2) {
    int u = u2 * 256 + tid;
    int chunk = u >> 6, lane = u & 63;
    int ent = ent0 + chunk * 16 + (lane & 15);
    if (ent > lim - 1) ent = lim - 1;
    int tok = etok[ent];
    const float4* s = (const float4*)(x + (size_t)tok * DDIM + kt * 32 + ((lane >> 4) << 3));
    float4 a = s[0], b = s[1];
    union { unsigned short h[8]; i32x4 v; } o;
    o.h[0] = f2bf(a.x); o.h[1] = f2bf(a.y); o.h[2] = f2bf(a.z); o.h[3] = f2bf(a.w);
    o.h[4] = f2bf(b.x); o.h[5] = f2bf(b.y); o.h[6] = f2bf(b.z); o.h[7] = f2bf(b.w);
    ((i32x4*)xgp)[(size_t)(page * 32 + kt) * 512 + u] = o.v;
  }
}

// ------- weights -> B-pretile: [e][ntile128][ktile32][chunk 8][lane 64][8] bf16 -------
// element: n = ntile*128 + chunk*16 + (lane&15); k = ktile*32 + (lane>>4)*8 + i
__global__ __launch_bounds__(256) void pretile_w(const float* __restrict__ src,
                                                 unsigned short* __restrict__ dst,
                                                 int Kdim, int Ndim) {
  __shared__ unsigned short t16[64][266];
  int NB = Ndim >> 8, KB = Kdim >> 6;
  int bid = blockIdx.x;
  int kblk = bid % KB; int rest = bid / KB;
  int nblk = rest % NB; int e = rest / NB;
  const float* s = src + ((size_t)e * Kdim + ((size_t)kblk << 6)) * Ndim + ((size_t)nblk << 8);
  int tid = threadIdx.x;
  int cp = tid & 127, rh = tid >> 7;
#pragma unroll
  for (int rr = 0; rr < 32; ++rr) {
    int r = rh * 32 + rr;
    float2 v = *(const float2*)(s + (size_t)r * Ndim + 2 * cp);
    unsigned int pk = (unsigned int)f2bf(v.x) | ((unsigned int)f2bf(v.y) << 16);
    *(unsigned int*)&t16[r][2 * cp] = pk;
  }
  __syncthreads();
  int NT = Ndim >> 7, KT = Kdim >> 5;
#pragma unroll
  for (int it = 0; it < 8; ++it) {
    int u = it * 256 + tid;  // 0..2047
    int nt2 = u >> 10, kt2 = (u >> 9) & 1, chunk = (u >> 6) & 7, lane = u & 63;
    int nl = nt2 * 128 + chunk * 16 + (lane & 15);
    int kl = kt2 * 32 + ((lane >> 4) << 3);
    union { unsigned short h[8]; i32x4 v; } o;
#pragma unroll
    for (int i = 0; i < 8; ++i) o.h[i] = t16[kl + i][nl];
    size_t idx = ((((size_t)e * NT + nblk * 2 + nt2) * KT + kblk * 2 + kt2) << 9) + (u & 511);
    ((i32x4*)dst)[idx] = o.v;
  }
}

// ---- GEMM: 128x128 tile, BK=32, 4 waves, 32 KB LDS, 4 blocks/CU ----
// All operands fragment-major -> linear gloads, immediate-offset ds_reads.

template <int MODE>
__global__ __launch_bounds__(256, 4) void moe_gemm(
    const unsigned short* __restrict__ Apre,  // pretile pages (xgp or hbuf)
    const unsigned short* __restrict__ Bpre,  // pretile weights
    const float* __restrict__ bias,
    const int* __restrict__ meta,
    const float* __restrict__ ewgt,
    unsigned short* __restrict__ Hbuf,
    float* __restrict__ Ybuf,
    int AKT, int BtNT, int BtKT, int ntg0, int kt0B,
    int nk, int biasOff, int bstr, int sIsZero, int KT_H) {
  const int* offsets = meta + 16;
  int ntiles = meta[48];
  int NX = gridDim.x;
  int lid = blockIdx.x + NX * blockIdx.y;
  int Ntot = NX * ntiles;
  if (lid >= Ntot) return;
  int q = Ntot >> 3, r = Ntot & 7;
  int xcd = lid & 7, pos = lid >> 3;
  int nlid = (xcd < r ? xcd * (q + 1) : r * (q + 1) + (xcd - r) * q) + pos;
  int nt = nlid / ntiles;
  int mti = nlid - nt * ntiles;
  int te = meta[64 + mti];
  int e = te & 255, mt = te >> 8;
  int off = offsets[e], cnt = offsets[e + 1] - off;

  // [2 slots][A 8K | B 8K]
  __shared__ __align__(128) char lds[32768];

  int tid = threadIdx.x, lane = tid & 63, wid = tid >> 6;
  int wr = wid >> 1, wc = wid & 1;
  int fr = lane & 15, fu = lane >> 4;

  const char* srcA = (const char*)Apre + ((size_t)mti * AKT << 13) + tid * 16;
  const char* srcB = (const char*)Bpre +
      ((((size_t)e * BtNT + ntg0 + nt) * BtKT + kt0B) << 13) + tid * 16;

  const char* rdA0 = lds + wr * 4096 + lane * 16;
  const char* rdB0 = lds + 8192 + wc * 4096 + lane * 16;
  char* stA = lds + tid * 16;

#define STAGE(Tn) do { \
    size_t _ko = (size_t)(Tn) << 13; \
    char* _d = stA + (((Tn) & 1) << 14); \
    gload16(srcA + _ko, _d); gload16(srcA + _ko + 4096, _d + 4096); \
    gload16(srcB + _ko, _d + 8192); gload16(srcB + _ko + 4096, _d + 12288); } while (0)

  f32x4 acc[4][4];
#pragma unroll
  for (int m = 0; m < 4; ++m)
#pragma unroll
    for (int n = 0; n < 4; ++n) acc[m][n] = (f32x4){0.f, 0.f, 0.f, 0.f};

  STAGE(0);
  VMWAIT(0);
  bar();

  for (int T = 0; T < nk; ++T) {
    if (T + 1 < nk) STAGE(T + 1);
    const char* a = rdA0 + ((T & 1) << 14);
    const char* b = rdB0 + ((T & 1) << 14);
    bf16x8 af[4], bg[4];
#pragma unroll
    for (int m = 0; m < 4; ++m) af[m] = *(const bf16x8*)(a + m * 1024);
#pragma unroll
    for (int n = 0; n < 4; ++n) bg[n] = *(const bf16x8*)(b + n * 1024);
    __builtin_amdgcn_s_setprio(1);
#pragma unroll
    for (int m = 0; m < 4; ++m)
#pragma unroll
      for (int n = 0; n < 4; ++n)
        acc[m][n] = __builtin_amdgcn_mfma_f32_16x16x32_bf16(af[m], bg[n], acc[m][n], 0, 0, 0);
    __builtin_amdgcn_s_setprio(0);
    VMWAIT(0);
    bar();
  }
#undef STAGE

  if (MODE == 0) {
    unsigned short* page = Hbuf + (size_t)mti * KT_H * 4096;
#pragma unroll
    for (int m = 0; m < 4; ++m) {
      int chunk = wr * 4 + m;
#pragma unroll
      for (int r = 0; r < 4; ++r) {
        int el = wr * 64 + m * 16 + fu * 4 + r;
        int gm = mt * 128 + el;
        if (gm < cnt) {
          int lsub = fu * 4 + r;
#pragma unroll
          for (int n = 0; n < 4; ++n) {
            int hcol = nt * 128 + wc * 64 + n * 16 + fr;
            float v = acc[m][n][r] + bias[e * bstr + biasOff + hcol];
            v = v / (1.f + __expf(-v));
            int ktile = hcol >> 5;
            int lanep = lsub + (((hcol >> 3) & 3) << 4);
            page[(((ktile << 3) + chunk) << 9) + (lanep << 3) + (hcol & 7)] = f2bf(v);
          }
        }
      }
    }
  } else {
#pragma unroll
    for (int m = 0; m < 4; ++m) {
#pragma unroll
      for (int r = 0; r < 4; ++r) {
        int el = wr * 64 + m * 16 + fu * 4 + r;
        int gm = mt * 128 + el;
        if (gm < cnt) {
          int ent = off + gm;
          float wgt = ewgt[ent];
          float* yrow = Ybuf + (size_t)ent * DDIM;
#pragma unroll
          for (int n = 0; n < 4; ++n) {
            int col = nt * 128 + wc * 64 + n * 16 + fr;
            float v = acc[m][n][r];
            if (sIsZero) {
              v = (v + bias[e * bstr + col]) * wgt;
              yrow[col] = v;
            } else {
              yrow[col] += v * wgt;
            }
          }
        }
      }
    }
  }
}

// ---------------- combine: out[t] = ybuf[inv0] (+ ybuf[inv1]) ----------------

__global__ __launch_bounds__(256) void combine(const float* __restrict__ yb,
                                               const int* __restrict__ inv,
                                               float* __restrict__ out) {
  int t = blockIdx.x, c = threadIdx.x;
  int p = inv[2 * t], q2 = inv[2 * t + 1];
  float4 v = ((const float4*)(yb + (size_t)p * DDIM))[c];
  if (q2 >= 0) {
    float4 w = ((const float4*)(yb + (size_t)q2 * DDIM))[c];
    v.x += w.x; v.y += w.y; v.z += w.z; v.w += w.w;
  }
  ((float4*)(out + (size_t)t * DDIM))[c] = v;
}

// ---------------- host launch ----------------

extern "C" void kernel_launch(void* const* d_in, const int* in_sizes, int n_in,
                              void* d_out, int out_size, void* d_ws, size_t ws_size,
                              hipStream_t stream) {
  (void)in_sizes; (void)n_in; (void)out_size;
  const float* x = (const float*)d_in[0];
  const int* eidx = (const int*)d_in[1];
  const float* ew = (const float*)d_in[2];
  const float* w1 = (const float*)d_in[3];
  const float* b1 = (const float*)d_in[4];
  const float* w2 = (const float*)d_in[5];
  const float* b2 = (const float*)d_in[6];
  float* out = (float*)d_out;

  char* w = (char*)d_ws;
  size_t o_meta = 0;
  size_t o_etok = 4096;
  size_t o_ewgt = o_etok + (size_t)MAXENT * 4;
  size_t o_inv  = o_ewgt + (size_t)MAXENT * 4;
  size_t o_xgp  = o_inv + (size_t)TOKENS * 2 * 4;
  size_t o_w1t  = o_xgp + (size_t)MAXTILES * 32 * 8192;             // 35.7 MB
  size_t o_w2t  = o_w1t + (size_t)NEXP * DDIM * HDIM * 2;           // +64 MB
  size_t o_yb   = o_w2t + (size_t)NEXP * DDIM * HDIM * 2;           // +64 MB
  size_t o_h    = o_yb + (size_t)MAXENT * DDIM * 4;                 // +64 MB

  int S = 1;
  while (S < 16) {
    size_t need = o_h + (size_t)MAXTILES * 128 * (HDIM / S) * 2;
    if (need <= ws_size) break;
    S *= 2;
  }
  int HC = HDIM / S;
  int KT_H = HC >> 5;

  int* meta = (int*)(w + o_meta);
  int* etok = (int*)(w + o_etok);
  float* ewgt = (float*)(w + o_ewgt);
  int* inv = (int*)(w + o_inv);
  unsigned short* xgp = (unsigned short*)(w + o_xgp);
  unsigned short* w1t = (unsigned short*)(w + o_w1t);
  unsigned short* w2t = (unsigned short*)(w + o_w2t);
  float* ybuf = (float*)(w + o_yb);
  unsigned short* hbuf = (unsigned short*)(w + o_h);

  hipMemsetAsync(w + o_meta, 0, 4096, stream);

  moe_count<<<TOKENS / 256, 256, 0, stream>>>(eidx, meta);
  moe_scan<<<1, 64, 0, stream>>>(meta);
  moe_scatter<<<TOKENS / 256, 256, 0, stream>>>(eidx, ew, meta, etok, ewgt, inv);
  gather_pre<<<dim3(MAXTILES, DDIM / 32), 256, 0, stream>>>(x, etok, meta, xgp);
  pretile_w<<<NEXP * (HDIM >> 8) * (DDIM >> 6), 256, 0, stream>>>(w1, w1t, DDIM, HDIM);
  pretile_w<<<NEXP * (DDIM >> 8) * (HDIM >> 6), 256, 0, stream>>>(w2, w2t, HDIM, DDIM);

  for (int s = 0; s < S; ++s) {
    // MODE 0: xgp[1024] @ w1t -> silu -> hbuf (pretile pages over HC)
    moe_gemm<0><<<dim3(HC / 128, MAXTILES), 256, 0, stream>>>(
        xgp, w1t, b1, meta, ewgt, hbuf, nullptr,
        /*AKT*/ DDIM >> 5, /*BtNT*/ HDIM >> 7, /*BtKT*/ DDIM >> 5,
        /*ntg0*/ (s * HC) >> 7, /*kt0B*/ 0,
        /*nk*/ DDIM >> 5, /*biasOff*/ s * HC, /*bstr*/ HDIM, 1, KT_H);
    // MODE 1: hbuf[HC] @ w2t -> ybuf (accumulate across s)
    moe_gemm<1><<<dim3(DDIM / 128, MAXTILES), 256, 0, stream>>>(
        hbuf, w2t, b2, meta, ewgt, nullptr, ybuf,
        /*AKT*/ KT_H, /*BtNT*/ DDIM >> 7, /*BtKT*/ HDIM >> 5,
        /*ntg0*/ 0, /*kt0B*/ (s * HC) >> 5,
        /*nk*/ KT_H, /*biasOff*/ 0, /*bstr*/ DDIM, (s == 0) ? 1 : 0, KT_H);
  }
  combine<<<TOKENS, 256, 0, stream>>>(ybuf, inv, out);
}

// Round 9
// 563.818 us; speedup vs baseline: 1.0901x; 1.0901x over previous
//
#include <hip/hip_runtime.h>
#include <hip/hip_bf16.h>
#include <stdint.h>

#define TOKENS 8192
#define DDIM 1024
#define HDIM 4096
#define NEXP 8
#define MAXENT 16384
#define MAXTILES 72

typedef __attribute__((ext_vector_type(4))) float f32x4;
typedef __attribute__((ext_vector_type(8))) short bf16x8;
typedef __attribute__((ext_vector_type(4))) int i32x4;

__device__ __forceinline__ unsigned short f2bf(float f) {
  __hip_bfloat16 h = __float2bfloat16(f);
  return __builtin_bit_cast(unsigned short, h);
}

__device__ __forceinline__ void gload16(const void* g, void* l) {
  __builtin_amdgcn_global_load_lds(
      (const __attribute__((address_space(1))) unsigned int*)g,
      (__attribute__((address_space(3))) unsigned int*)l, 16, 0, 0);
}

__device__ __forceinline__ void bar0() {
  asm volatile("" ::: "memory");
  __builtin_amdgcn_s_barrier();
  asm volatile("" ::: "memory");
}

#define LGKM0 asm volatile("s_waitcnt lgkmcnt(0)" ::: "memory")
#define VMWAIT(N) asm volatile("s_waitcnt vmcnt(" #N ")" ::: "memory")

// ---------------- prep ----------------

__global__ void moe_count(const int* __restrict__ idx, int* __restrict__ meta) {
  int t = blockIdx.x * 256 + threadIdx.x;
  if (t >= TOKENS) return;
  int e0 = idx[2 * t], e1 = idx[2 * t + 1];
  atomicAdd(&meta[e0], 1);
  if (e1 != e0) atomicAdd(&meta[e1], 1);
}

__global__ void moe_scan(int* __restrict__ meta) {
  if (threadIdx.x != 0 || blockIdx.x != 0) return;
  int s = 0;
  for (int e = 0; e < NEXP; ++e) { meta[16 + e] = s; meta[32 + e] = s; s += meta[e]; }
  meta[16 + NEXP] = s;
  int nt = 0;
  for (int e = 0; e < NEXP; ++e) {
    int m = (meta[e] + 255) >> 8;  // 256-entry tiles
    for (int t = 0; t < m; ++t) meta[64 + nt++] = e | (t << 8);
  }
  meta[48] = nt;
}

__global__ void moe_scatter(const int* __restrict__ idx, const float* __restrict__ ew,
                            int* __restrict__ meta, int* __restrict__ etok,
                            float* __restrict__ ewgt, int* __restrict__ inv) {
  int t = blockIdx.x * 256 + threadIdx.x;
  if (t >= TOKENS) return;
  int e0 = idx[2 * t], e1 = idx[2 * t + 1];
  float a = ew[2 * t], b = ew[2 * t + 1];
  if (e0 == e1) {
    int p = atomicAdd(&meta[32 + e0], 1);
    etok[p] = t; ewgt[p] = a + b;
    inv[2 * t] = p; inv[2 * t + 1] = -1;
  } else {
    int p = atomicAdd(&meta[32 + e0], 1);
    etok[p] = t; ewgt[p] = a;
    int q = atomicAdd(&meta[32 + e1], 1);
    etok[q] = t; ewgt[q] = b;
    inv[2 * t] = p; inv[2 * t + 1] = q;
  }
}

// ---- gather x -> A-pretile pages: [page256][kt32][chunk16][lane64][8] bf16 ----
// ent = ent0 + chunk*16 + (lane&15); k = kt*32 + (lane>>4)*8 + i

__global__ __launch_bounds__(256) void gather_pre(const float* __restrict__ x,
                                                  const int* __restrict__ etok,
                                                  const int* __restrict__ meta,
                                                  unsigned short* __restrict__ xgp) {
  int ntiles = meta[48];
  int page = blockIdx.x, kt = blockIdx.y;
  if (page >= ntiles) return;
  int te = meta[64 + page];
  int e = te & 255, mt = te >> 8;
  int ent0 = meta[16 + e] + mt * 256, lim = meta[16 + e + 1];
  int tid = threadIdx.x;
#pragma unroll
  for (int it = 0; it < 4; ++it) {
    int u = it * 256 + tid;  // 0..1023
    int chunk = u >> 6, lane = u & 63;
    int ent = ent0 + chunk * 16 + (lane & 15);
    if (ent > lim - 1) ent = lim - 1;
    int tok = etok[ent];
    const float4* s = (const float4*)(x + (size_t)tok * DDIM + kt * 32 + ((lane >> 4) << 3));
    float4 a = s[0], b = s[1];
    union { unsigned short h[8]; i32x4 v; } o;
    o.h[0] = f2bf(a.x); o.h[1] = f2bf(a.y); o.h[2] = f2bf(a.z); o.h[3] = f2bf(a.w);
    o.h[4] = f2bf(b.x); o.h[5] = f2bf(b.y); o.h[6] = f2bf(b.z); o.h[7] = f2bf(b.w);
    ((i32x4*)xgp)[(size_t)(page * 32 + kt) * 1024 + u] = o.v;
  }
}

// ---- weights -> B-pretile: [e][nt256][kt32][chunk16][lane64][8] bf16 ----
// n = nt*256 + chunk*16 + (lane&15); k = kt*32 + (lane>>4)*8 + i
__global__ __launch_bounds__(256) void pretile_w(const float* __restrict__ src,
                                                 unsigned short* __restrict__ dst,
                                                 int Kdim, int Ndim) {
  __shared__ unsigned short t16[64][266];
  int NB = Ndim >> 8, KB = Kdim >> 6;
  int bid = blockIdx.x;
  int kblk = bid % KB; int rest = bid / KB;
  int nblk = rest % NB; int e = rest / NB;
  const float* s = src + ((size_t)e * Kdim + ((size_t)kblk << 6)) * Ndim + ((size_t)nblk << 8);
  int tid = threadIdx.x;
  int cp = tid & 127, rh = tid >> 7;
#pragma unroll
  for (int rr = 0; rr < 32; ++rr) {
    int r = rh * 32 + rr;
    float2 v = *(const float2*)(s + (size_t)r * Ndim + 2 * cp);
    unsigned int pk = (unsigned int)f2bf(v.x) | ((unsigned int)f2bf(v.y) << 16);
    *(unsigned int*)&t16[r][2 * cp] = pk;
  }
  __syncthreads();
  int KT32 = Kdim >> 5;
#pragma unroll
  for (int it = 0; it < 8; ++it) {
    int u = it * 256 + tid;   // 0..2047
    int kt2 = u >> 10, rem = u & 1023;
    int chunk = rem >> 6, lane = rem & 63;
    int nl = chunk * 16 + (lane & 15);
    int kl = kt2 * 32 + ((lane >> 4) << 3);
    union { unsigned short h[8]; i32x4 v; } o;
#pragma unroll
    for (int i = 0; i < 8; ++i) o.h[i] = t16[kl + i][nl];
    size_t idx = (((size_t)e * NB + nblk) * KT32 + kblk * 2 + kt2) * 1024 + rem;
    ((i32x4*)dst)[idx] = o.v;
  }
}

// ---- GEMM: 256x256, BK=32, 8 waves (2M x 4N), 4-deep 16KB K-slot ring,
//      2 fine phases/K-tile, counted vmcnt(8), lgkmcnt(0)+setprio per cluster ----

template <int MODE>
__global__ __launch_bounds__(512, 2) void moe_gemm(
    const unsigned short* __restrict__ Apre,  // pages [*][AKT][16KB]
    const unsigned short* __restrict__ Bpre,  // [e][BtNT][BtKT][16KB]
    const float* __restrict__ bias,
    const int* __restrict__ meta,
    const float* __restrict__ ewgt,
    unsigned short* __restrict__ Hbuf,
    float* __restrict__ Ybuf,
    int AKT, int BtNT, int BtKT, int ntg0, int kt0B,
    int nk, int biasOff, int bstr, int sIsZero, int KT_H) {
  const int* offsets = meta + 16;
  int ntiles = meta[48];
  int NX = gridDim.x;
  int lid = blockIdx.x + NX * blockIdx.y;
  int Ntot = NX * ntiles;
  if (lid >= Ntot) return;
  int q = Ntot >> 3, r = Ntot & 7;
  int xcd = lid & 7, pos = lid >> 3;
  int nlid = (xcd < r ? xcd * (q + 1) : r * (q + 1) + (xcd - r) * q) + pos;
  int nt = nlid / ntiles;
  int mti = nlid - nt * ntiles;
  int te = meta[64 + mti];
  int e = te & 255, mt = te >> 8;
  int off = offsets[e], cnt = offsets[e + 1] - off;

  // A ring [0,64K): 4 slots x 16 KiB. B ring [64K,128K): 4 slots x 16 KiB.
  __shared__ __align__(128) char lds[131072];

  int tid = threadIdx.x, lane = tid & 63, wid = tid >> 6;
  int wr = wid >> 2, wc = wid & 3;
  int fr = lane & 15, fu = lane >> 4;

  const char* srcA = (const char*)Apre + ((size_t)mti * AKT << 14) + (tid << 4);
  const char* srcB = (const char*)Bpre +
      ((((size_t)e * BtNT + ntg0 + nt) * BtKT + kt0B) << 14) + (tid << 4);

#define STAGE_A(Tn) do { \
    char* _d = lds + (((Tn) & 3) << 14) + (tid << 4); \
    const char* _s = srcA + ((size_t)(Tn) << 14); \
    gload16(_s, _d); gload16(_s + 8192, _d + 8192); } while (0)
#define STAGE_B(Tn) do { \
    char* _d = lds + 65536 + (((Tn) & 3) << 14) + (tid << 4); \
    const char* _s = srcB + ((size_t)(Tn) << 14); \
    gload16(_s, _d); gload16(_s + 8192, _d + 8192); } while (0)

  f32x4 acc[8][4];
#pragma unroll
  for (int m = 0; m < 8; ++m)
#pragma unroll
    for (int n = 0; n < 4; ++n) acc[m][n] = (f32x4){0.f, 0.f, 0.f, 0.f};

  // prologue: stage K-tiles 0,1,2 (12 loads/thread); wait until kt0 landed.
  STAGE_A(0); STAGE_B(0);
  STAGE_A(1); STAGE_B(1);
  STAGE_A(2); STAGE_B(2);
  VMWAIT(8);
  bar0();

  for (int kt = 0; kt < nk; ++kt) {
    const char* pa = lds + ((kt & 3) << 14) + (wr << 13) + (lane << 4);
    const char* pb = lds + 65536 + ((kt & 3) << 14) + (wc << 12) + (lane << 4);
    bool st = (kt + 3 < nk);

    // ---- phase A: A-frags mf0-3 + all B-frags; stage A(kt+3) ----
    bf16x8 a0 = *(const bf16x8*)(pa);
    bf16x8 a1 = *(const bf16x8*)(pa + 1024);
    bf16x8 a2 = *(const bf16x8*)(pa + 2048);
    bf16x8 a3 = *(const bf16x8*)(pa + 3072);
    bf16x8 bg[4];
#pragma unroll
    for (int n = 0; n < 4; ++n) bg[n] = *(const bf16x8*)(pb + n * 1024);
    if (st) STAGE_A(kt + 3);
    bar0();
    LGKM0;
    __builtin_amdgcn_s_setprio(1);
#pragma unroll
    for (int n = 0; n < 4; ++n) {
      acc[0][n] = __builtin_amdgcn_mfma_f32_16x16x32_bf16(a0, bg[n], acc[0][n], 0, 0, 0);
      acc[1][n] = __builtin_amdgcn_mfma_f32_16x16x32_bf16(a1, bg[n], acc[1][n], 0, 0, 0);
      acc[2][n] = __builtin_amdgcn_mfma_f32_16x16x32_bf16(a2, bg[n], acc[2][n], 0, 0, 0);
      acc[3][n] = __builtin_amdgcn_mfma_f32_16x16x32_bf16(a3, bg[n], acc[3][n], 0, 0, 0);
    }
    __builtin_amdgcn_s_setprio(0);
    bar0();

    // ---- phase B: A-frags mf4-7 (B reused); stage B(kt+3); counted drain ----
    a0 = *(const bf16x8*)(pa + 4096);
    a1 = *(const bf16x8*)(pa + 5120);
    a2 = *(const bf16x8*)(pa + 6144);
    a3 = *(const bf16x8*)(pa + 7168);
    if (st) STAGE_B(kt + 3);
    bar0();
    LGKM0;
    __builtin_amdgcn_s_setprio(1);
#pragma unroll
    for (int n = 0; n < 4; ++n) {
      acc[4][n] = __builtin_amdgcn_mfma_f32_16x16x32_bf16(a0, bg[n], acc[4][n], 0, 0, 0);
      acc[5][n] = __builtin_amdgcn_mfma_f32_16x16x32_bf16(a1, bg[n], acc[5][n], 0, 0, 0);
      acc[6][n] = __builtin_amdgcn_mfma_f32_16x16x32_bf16(a2, bg[n], acc[6][n], 0, 0, 0);
      acc[7][n] = __builtin_amdgcn_mfma_f32_16x16x32_bf16(a3, bg[n], acc[7][n], 0, 0, 0);
    }
    __builtin_amdgcn_s_setprio(0);
    if (kt < nk - 3)       { VMWAIT(8); }
    else if (kt == nk - 3) { VMWAIT(4); }
    else if (kt == nk - 2) { VMWAIT(0); }
    bar0();
  }
#undef STAGE_A
#undef STAGE_B

  if (MODE == 0) {
    // write hbuf page in A-pretile layout for MODE1
    unsigned short* page = Hbuf + (size_t)mti * KT_H * 8192;
#pragma unroll
    for (int m = 0; m < 8; ++m) {
#pragma unroll
      for (int r = 0; r < 4; ++r) {
        int row = wr * 128 + m * 16 + fu * 4 + r;
        int gm = mt * 256 + row;
        if (gm < cnt) {
#pragma unroll
          for (int n = 0; n < 4; ++n) {
            int lc = nt * 256 + wc * 64 + n * 16 + fr;
            float v = acc[m][n][r] + bias[e * bstr + biasOff + lc];
            v = v / (1.f + __expf(-v));
            int kt = lc >> 5;
            int idx = (((kt * 16 + (row >> 4)) << 9) +
                       (((row & 15) + (((lc >> 3) & 3) << 4)) << 3) + (lc & 7));
            page[idx] = f2bf(v);
          }
        }
      }
    }
  } else {
#pragma unroll
    for (int m = 0; m < 8; ++m) {
#pragma unroll
      for (int r = 0; r < 4; ++r) {
        int row = wr * 128 + m * 16 + fu * 4 + r;
        int gm = mt * 256 + row;
        if (gm < cnt) {
          int ent = off + gm;
          float wgt = ewgt[ent];
          float* yrow = Ybuf + (size_t)ent * DDIM;
#pragma unroll
          for (int n = 0; n < 4; ++n) {
            int col = nt * 256 + wc * 64 + n * 16 + fr;
            float v = acc[m][n][r];
            if (sIsZero) {
              yrow[col] = (v + bias[e * bstr + col]) * wgt;
            } else {
              yrow[col] += v * wgt;
            }
          }
        }
      }
    }
  }
}

// ---------------- combine: out[t] = ybuf[inv0] (+ ybuf[inv1]) ----------------

__global__ __launch_bounds__(256) void combine(const float* __restrict__ yb,
                                               const int* __restrict__ inv,
                                               float* __restrict__ out) {
  int t = blockIdx.x, c = threadIdx.x;
  int p = inv[2 * t], q2 = inv[2 * t + 1];
  float4 v = ((const float4*)(yb + (size_t)p * DDIM))[c];
  if (q2 >= 0) {
    float4 w = ((const float4*)(yb + (size_t)q2 * DDIM))[c];
    v.x += w.x; v.y += w.y; v.z += w.z; v.w += w.w;
  }
  ((float4*)(out + (size_t)t * DDIM))[c] = v;
}

// ---------------- host launch ----------------

extern "C" void kernel_launch(void* const* d_in, const int* in_sizes, int n_in,
                              void* d_out, int out_size, void* d_ws, size_t ws_size,
                              hipStream_t stream) {
  (void)in_sizes; (void)n_in; (void)out_size;
  const float* x = (const float*)d_in[0];
  const int* eidx = (const int*)d_in[1];
  const float* ew = (const float*)d_in[2];
  const float* w1 = (const float*)d_in[3];
  const float* b1 = (const float*)d_in[4];
  const float* w2 = (const float*)d_in[5];
  const float* b2 = (const float*)d_in[6];
  float* out = (float*)d_out;

  char* w = (char*)d_ws;
  size_t o_meta = 0;
  size_t o_etok = 4096;
  size_t o_ewgt = o_etok + (size_t)MAXENT * 4;
  size_t o_inv  = o_ewgt + (size_t)MAXENT * 4;
  size_t o_xgp  = o_inv + (size_t)TOKENS * 2 * 4;
  size_t o_w1t  = o_xgp + (size_t)MAXTILES * 32 * 16384;            // 37.7 MB
  size_t o_w2t  = o_w1t + (size_t)NEXP * DDIM * HDIM * 2;           // +64 MB
  size_t o_yb   = o_w2t + (size_t)NEXP * DDIM * HDIM * 2;           // +64 MB
  size_t o_h    = o_yb + (size_t)MAXENT * DDIM * 4;                 // +64 MB

  int S = 1;
  while (S < 16) {
    size_t need = o_h + (size_t)MAXTILES * ((HDIM / S) >> 5) * 16384;
    if (need <= ws_size) break;
    S *= 2;
  }
  int HC = HDIM / S;
  int KT_H = HC >> 5;

  int* meta = (int*)(w + o_meta);
  int* etok = (int*)(w + o_etok);
  float* ewgt = (float*)(w + o_ewgt);
  int* inv = (int*)(w + o_inv);
  unsigned short* xgp = (unsigned short*)(w + o_xgp);
  unsigned short* w1t = (unsigned short*)(w + o_w1t);
  unsigned short* w2t = (unsigned short*)(w + o_w2t);
  float* ybuf = (float*)(w + o_yb);
  unsigned short* hbuf = (unsigned short*)(w + o_h);

  hipMemsetAsync(w + o_meta, 0, 4096, stream);

  moe_count<<<TOKENS / 256, 256, 0, stream>>>(eidx, meta);
  moe_scan<<<1, 64, 0, stream>>>(meta);
  moe_scatter<<<TOKENS / 256, 256, 0, stream>>>(eidx, ew, meta, etok, ewgt, inv);
  gather_pre<<<dim3(MAXTILES, DDIM / 32), 256, 0, stream>>>(x, etok, meta, xgp);
  pretile_w<<<NEXP * (HDIM >> 8) * (DDIM >> 6), 256, 0, stream>>>(w1, w1t, DDIM, HDIM);
  pretile_w<<<NEXP * (DDIM >> 8) * (HDIM >> 6), 256, 0, stream>>>(w2, w2t, HDIM, DDIM);

  for (int s = 0; s < S; ++s) {
    // MODE 0: xgp @ w1t -> silu -> hbuf (pretile pages over HC)
    moe_gemm<0><<<dim3(HC / 256, MAXTILES), 512, 0, stream>>>(
        xgp, w1t, b1, meta, ewgt, hbuf, nullptr,
        /*AKT*/ DDIM >> 5, /*BtNT*/ HDIM >> 8, /*BtKT*/ DDIM >> 5,
        /*ntg0*/ (s * HC) >> 8, /*kt0B*/ 0,
        /*nk*/ DDIM >> 5, /*biasOff*/ s * HC, /*bstr*/ HDIM, 1, KT_H);
    // MODE 1: hbuf @ w2t -> ybuf (accumulate across s)
    moe_gemm<1><<<dim3(DDIM / 256, MAXTILES), 512, 0, stream>>>(
        hbuf, w2t, b2, meta, ewgt, nullptr, ybuf,
        /*AKT*/ KT_H, /*BtNT*/ DDIM >> 8, /*BtKT*/ HDIM >> 5,
        /*ntg0*/ 0, /*kt0B*/ (s * HC) >> 5,
        /*nk*/ KT_H, /*biasOff*/ 0, /*bstr*/ DDIM, (s == 0) ? 1 : 0, KT_H);
  }
  combine<<<TOKENS, 256, 0, stream>>>(ybuf, inv, out);
}